// Round 6
// baseline (203.401 us; speedup 1.0000x reference)
//
#include <hip/hip_runtime.h>
#include <hip/hip_bf16.h>

#define E 1024
#define DK 64
#define SEQ 4096
#define NB 4
// 0.125 * log2(e): scores arrive pre-multiplied so softmax = exp2(s) = v_exp_f32
#define KSCALE 0.18033688011112042f

typedef short bf16x8 __attribute__((ext_vector_type(8)));
typedef short bf16x4 __attribute__((ext_vector_type(4)));
typedef float f32x4 __attribute__((ext_vector_type(4)));

typedef const __attribute__((address_space(1))) unsigned int* gcp;
typedef __attribute__((address_space(3))) unsigned int* lcp;

__device__ inline unsigned short f2bf(float f) {
    unsigned int u = __float_as_uint(f);
    u += 0x7fff + ((u >> 16) & 1);   // round-to-nearest-even
    return (unsigned short)(u >> 16);
}
__device__ inline unsigned int cvtpk(float a, float b) {
    union { __hip_bfloat162 h; unsigned int u; } x;
    x.h = __float22bfloat162_rn(make_float2(a, b));
    return x.u;
}
__device__ inline bf16x8 cvt8(f32x4 a, f32x4 b) {
    union { unsigned int u[4]; bf16x8 v; } x;
    x.u[0] = cvtpk(a[0], a[1]); x.u[1] = cvtpk(a[2], a[3]);
    x.u[2] = cvtpk(b[0], b[1]); x.u[3] = cvtpk(b[2], b[3]);
    return x.v;
}

// ---------------- Kernel 0: W [1024][64] fp32 -> Wt [64][1024] bf16 (LDS transpose) --------
__global__ __launch_bounds__(256) void wt_kernel(
    const float* __restrict__ Wq, const float* __restrict__ Wk, const float* __restrict__ Wv,
    unsigned short* __restrict__ wtq, unsigned short* __restrict__ wtk, unsigned short* __restrict__ wtv)
{
    const float* src; unsigned short* dst;
    if (blockIdx.y == 0)      { src = Wq; dst = wtq; }
    else if (blockIdx.y == 1) { src = Wk; dst = wtk; }
    else                      { src = Wv; dst = wtv; }
    const int tid = threadIdx.x;
    const int e0 = blockIdx.x * 64;
    __shared__ float Ws[64][65];
    #pragma unroll
    for (int i = 0; i < 4; ++i) {
        int flat = i * 256 + tid;
        int r = flat >> 4;
        int c4 = (flat & 15) << 2;
        float4 v = *reinterpret_cast<const float4*>(&src[(size_t)(e0 + r) * DK + c4]);
        Ws[c4 + 0][r] = v.x; Ws[c4 + 1][r] = v.y; Ws[c4 + 2][r] = v.z; Ws[c4 + 3][r] = v.w;
    }
    __syncthreads();
    #pragma unroll
    for (int i = 0; i < 4; ++i) {
        int flat = i * 256 + tid;
        int c = flat >> 4;
        int r4 = (flat & 15) << 2;
        ushort4 o;
        o.x = f2bf(Ws[c][r4 + 0]); o.y = f2bf(Ws[c][r4 + 1]);
        o.z = f2bf(Ws[c][r4 + 2]); o.w = f2bf(Ws[c][r4 + 3]);
        *reinterpret_cast<ushort4*>(&dst[(size_t)c * E + e0 + r4]) = o;
    }
}

// ---------------- Kernel 1: QKV projection — BK=128: half the barrier-drains ---------------
// R5 counters: MfmaUtil 3.9 / VALU 6.3 / HBM 16% / 0 conflicts -> ~93% stalled; per-iter
// time ~8.7k cyc vs ~500 cyc issue work. Cause: __syncthreads emits vmcnt(0) which drains
// the ENTIRE vmem queue (A prefetch + just-issued W DMA) every kb -> time ~ n_barriers x
// drain-constant. Fix: BK 64->128 halves the barrier count (16->8 iters), 2x work per
// drain. Same sync template, same swizzle involution (^(row&7), now 16 chunks/row ->
// 2-way LDS aliasing = free), and BIT-IDENTICAL accumulation order (kb-major, ks-minor
// sequence over 32-col chunks is unchanged). LDS 64 KB -> still 2 blocks/CU.
// launch_bounds (256,2): A dbuf is 64 VGPR now; avoid an R3-style spill at the 128 cap.
__global__ __launch_bounds__(256, 2) void proj_kernel(
    const float* __restrict__ in_q, const float* __restrict__ in_kv,
    const unsigned short* __restrict__ wtq, const unsigned short* __restrict__ wtk,
    const unsigned short* __restrict__ wtv,
    const float* __restrict__ bq, const float* __restrict__ bk, const float* __restrict__ bv,
    unsigned short* __restrict__ Qw, unsigned short* __restrict__ Kw, unsigned short* __restrict__ Vtw)
{
    const int tid = threadIdx.x;
    const int w = tid >> 6, lane = tid & 63, quad = lane >> 4, l16 = lane & 15;
    const int row0 = blockIdx.x * 64;
    const bool isQ = (blockIdx.y == 0);
    const float* Arow = (isQ ? in_q : in_kv) + (size_t)(row0 + w * 16 + l16) * E;
    const unsigned short* w0 = isQ ? wtq : wtk;

    __shared__ unsigned short W0s[2][8192];   // 16 KB per buf: 64 dk-rows x 128 E-cols
    __shared__ unsigned short W1s[2][8192];   // 32 KB (V path)

    // ---- W DMA geometry: instr g = w*4+i covers LDS [g*1024,+1024) = rows g*4+(lane>>4),
    // phys 16B-chunk lane&15; logical chunk = phys ^ (row&7); source = wt row r, 16B chunk.
    auto stageW = [&](int kb, int bb) {
        #pragma unroll
        for (int i = 0; i < 4; ++i) {
            int g = w * 4 + i;
            int r = g * 4 + (lane >> 4);
            int lc = (lane & 15) ^ (r & 7);
            __builtin_amdgcn_global_load_lds((gcp)(const void*)(w0 + (size_t)r * E + kb * 128 + lc * 8),
                                             (lcp)(void*)&W0s[bb][g * 512], 16, 0, 0);
            if (!isQ)
                __builtin_amdgcn_global_load_lds((gcp)(const void*)(wtv + (size_t)r * E + kb * 128 + lc * 8),
                                                 (lcp)(void*)&W1s[bb][g * 512], 16, 0, 0);
        }
    };

    // ---- prime: W tiles for kb=0 (async), A regs for kb=0 ----
    stageW(0, 0);
    f32x4 a_cur[8];
    #pragma unroll
    for (int ks = 0; ks < 4; ++ks)
        #pragma unroll
        for (int j = 0; j < 2; ++j)
            a_cur[ks * 2 + j] = *reinterpret_cast<const f32x4*>(Arow + ks * 32 + quad * 8 + j * 4);
    __syncthreads();

    f32x4 acc0[4] = {};
    f32x4 acc1[4] = {};

    for (int kb = 0; kb < 8; ++kb) {
        const int cur = kb & 1, nxt = cur ^ 1;
        f32x4 a_nxt[8];
        if (kb < 7) {
            const int ko = (kb + 1) * 128;
            stageW(kb + 1, nxt);
            const float* an = Arow + ko;
            #pragma unroll
            for (int ks = 0; ks < 4; ++ks)
                #pragma unroll
                for (int j = 0; j < 2; ++j)
                    a_nxt[ks * 2 + j] = *reinterpret_cast<const f32x4*>(an + ks * 32 + quad * 8 + j * 4);
        }
        // compute on cur (accumulation order identical to the BK=64 version)
        #pragma unroll
        for (int ks = 0; ks < 4; ++ks) {
            bf16x8 af = cvt8(a_cur[ks * 2], a_cur[ks * 2 + 1]);
            #pragma unroll
            for (int ct = 0; ct < 4; ++ct) {
                int brow = ct * 16 + l16;
                int pc = (ks * 4 + quad) ^ (brow & 7);
                bf16x8 b0 = *reinterpret_cast<const bf16x8*>(&W0s[cur][brow * 128 + pc * 8]);
                acc0[ct] = __builtin_amdgcn_mfma_f32_16x16x32_bf16(af, b0, acc0[ct], 0, 0, 0);
                if (!isQ) {
                    bf16x8 b1 = *reinterpret_cast<const bf16x8*>(&W1s[cur][brow * 128 + pc * 8]);
                    acc1[ct] = __builtin_amdgcn_mfma_f32_16x16x32_bf16(af, b1, acc1[ct], 0, 0, 0);
                }
            }
        }
        #pragma unroll
        for (int j = 0; j < 8; ++j) a_cur[j] = a_nxt[j];
        if (kb < 7) __syncthreads();
    }

    // epilogue: C/D layout col=lane&15, row=quad*4+reg
    const int orow0 = row0 + w * 16 + quad * 4;
    #pragma unroll
    for (int ct = 0; ct < 4; ++ct) {
        int col = ct * 16 + l16;
        if (isQ) {
            float bias = bq[col];
            #pragma unroll
            for (int r = 0; r < 4; ++r)
                Qw[(size_t)(orow0 + r) * DK + col] = f2bf(acc0[ct][r] + bias);
        } else {
            float biask = bk[col], biasv = bv[col];
            #pragma unroll
            for (int r = 0; r < 4; ++r) {
                int grow = orow0 + r;
                Kw[(size_t)grow * DK + col] = f2bf((acc0[ct][r] + biask) * KSCALE);
                int bb = grow >> 12;
                int tok = grow & 4095;
                Vtw[((size_t)(bb * 64 + col)) * SEQ + tok] = f2bf(acc1[ct][r] + biasv);
            }
        }
    }
}

// ---------------- Kernel 2: flash attention — q128 x key-half, LDS-shared K/V (R5) -------
__global__ __launch_bounds__(512) void attn_kernel(
    const unsigned short* __restrict__ Qw, const unsigned short* __restrict__ Kw,
    const unsigned short* __restrict__ Vtw, float* __restrict__ Opart, float* __restrict__ Lpart)
{
    const int tid = threadIdx.x;
    const int w = tid >> 6, lane = tid & 63, quad = lane >> 4, l16 = lane & 15;
    const int s = w & 3, h = w >> 2;
    const int kh = blockIdx.x & 1;                      // key half
    const int b  = (blockIdx.x >> 1) & 3;               // batch
    const int qt = blockIdx.x >> 3;                     // 0..31, 128-query tiles

    __shared__ unsigned short Klds[2][8192];   // [buf][key*64 + d], swizzled, 16 KB each
    __shared__ unsigned short Vlds[2][8192];   // [buf][d*128 + key], swizzled, 16 KB each
    __shared__ float LDSf[8][2][16][68];       // 69.6 KB (reduce only)
    __shared__ float LDSl[8][4][16];

    const unsigned short* Ksrc = Kw + ((size_t)b * SEQ + kh * 2048) * DK;   // rows of 128B
    const unsigned short* Vsrc = Vtw + (size_t)b * 64 * SEQ + kh * 2048;    // rows of 8192B

    const int g0 = w * 2, g1 = w * 2 + 1;
    const int krow0 = g0 * 8 + (lane >> 3), krow1 = g1 * 8 + (lane >> 3);
    const int kcol = ((lane & 7) ^ (lane >> 3)) << 4;
    const int vrow0 = g0 * 4 + (lane >> 4), vrow1 = g1 * 4 + (lane >> 4);
    const int vcol0 = ((lane & 15) ^ (vrow0 & 7)) << 4;
    const int vcol1 = ((lane & 15) ^ (vrow1 & 7)) << 4;

    auto stage = [&](int t, int bb) {
        const char* kb = (const char*)Ksrc + (size_t)t * 16384;
        __builtin_amdgcn_global_load_lds((gcp)(const void*)(kb + krow0 * 128 + kcol),
                                         (lcp)(void*)((char*)Klds[bb] + g0 * 1024), 16, 0, 0);
        __builtin_amdgcn_global_load_lds((gcp)(const void*)(kb + krow1 * 128 + kcol),
                                         (lcp)(void*)((char*)Klds[bb] + g1 * 1024), 16, 0, 0);
        const char* vb = (const char*)Vsrc + t * 256;
        __builtin_amdgcn_global_load_lds((gcp)(const void*)(vb + (size_t)vrow0 * 8192 + vcol0),
                                         (lcp)(void*)((char*)Vlds[bb] + g0 * 1024), 16, 0, 0);
        __builtin_amdgcn_global_load_lds((gcp)(const void*)(vb + (size_t)vrow1 * 8192 + vcol1),
                                         (lcp)(void*)((char*)Vlds[bb] + g1 * 1024), 16, 0, 0);
    };

    stage(0, 0);   // prime tile 0 while Q loads are in flight

    bf16x8 qfb[2][4];
    #pragma unroll
    for (int ks = 0; ks < 2; ++ks)
        #pragma unroll
        for (int ct = 0; ct < 4; ++ct)
            qfb[ks][ct] = *reinterpret_cast<const bf16x8*>(
                &Qw[((size_t)(b * SEQ + qt * 128 + h * 64 + ct * 16 + l16)) * DK + ks * 32 + quad * 8]);

    const int kxor = (l16 & 7) << 4;
    unsigned kf_off[2][2];
    unsigned va_off[2][4];
    #pragma unroll
    for (int t2 = 0; t2 < 2; ++t2) {
        const int kr = s * 32 + t2 * 16 + l16;
        kf_off[t2][0] = (unsigned)(kr * 128 + ((quad * 16) ^ kxor));
        kf_off[t2][1] = (unsigned)(kr * 128 + ((64 + quad * 16) ^ kxor));
        #pragma unroll
        for (int ct = 0; ct < 4; ++ct)
            va_off[t2][ct] = (unsigned)((ct * 16 + l16) * 256 +
                                        ((s * 64 + t2 * 32 + quad * 8) ^ kxor));
    }

    __syncthreads();

    float lp[4] = {0.f, 0.f, 0.f, 0.f};
    f32x4 o[4][4] = {};   // o[ct_d][ct_q]

    #pragma unroll 1
    for (int i = 0; i < 16; ++i) {
        const int cur = i & 1;
        if (i < 15) stage(i + 1, cur ^ 1);    // DMA next tile into other buffer

        #pragma unroll
        for (int t2 = 0; t2 < 2; ++t2) {
            bf16x8 kf0 = *reinterpret_cast<const bf16x8*>((const char*)Klds[cur] + kf_off[t2][0]);
            bf16x8 kf1 = *reinterpret_cast<const bf16x8*>((const char*)Klds[cur] + kf_off[t2][1]);
            bf16x4 va[4];
            #pragma unroll
            for (int ct = 0; ct < 4; ++ct)
                va[ct] = *reinterpret_cast<const bf16x4*>((const char*)Vlds[cur] + va_off[t2][ct]);

            f32x4 sacc[4] = {};
            #pragma unroll
            for (int ct = 0; ct < 4; ++ct) {
                sacc[ct] = __builtin_amdgcn_mfma_f32_16x16x32_bf16(kf0, qfb[0][ct], sacc[ct], 0, 0, 0);
                sacc[ct] = __builtin_amdgcn_mfma_f32_16x16x32_bf16(kf1, qfb[1][ct], sacc[ct], 0, 0, 0);
            }

            #pragma unroll
            for (int cq = 0; cq < 4; ++cq) {
                float p0 = __builtin_amdgcn_exp2f(sacc[cq][0]);
                float p1 = __builtin_amdgcn_exp2f(sacc[cq][1]);
                float p2 = __builtin_amdgcn_exp2f(sacc[cq][2]);
                float p3 = __builtin_amdgcn_exp2f(sacc[cq][3]);
                lp[cq] += (p0 + p1) + (p2 + p3);
                union { unsigned int u[2]; bf16x4 v; } pbu;
                pbu.u[0] = cvtpk(p0, p1);
                pbu.u[1] = cvtpk(p2, p3);
                bf16x4 pb = pbu.v;
                #pragma unroll
                for (int cd = 0; cd < 4; ++cd)
                    o[cd][cq] = __builtin_amdgcn_mfma_f32_16x16x16bf16_1k(va[cd], pb, o[cd][cq], 0, 0, 0);
            }
        }

        __syncthreads();   // next tile staged (vmcnt drained) + everyone done with cur
    }

    #pragma unroll
    for (int cq = 0; cq < 4; ++cq) {
        float t = lp[cq];
        t += __shfl_xor(t, 16, 64);
        t += __shfl_xor(t, 32, 64);
        lp[cq] = t;
    }
    if (lane < 16)
        #pragma unroll
        for (int cq = 0; cq < 4; ++cq)
            LDSl[w][cq][lane] = lp[cq];

    const int rowbase = b * SEQ + qt * 128;
    #pragma unroll
    for (int rr = 0; rr < 2; ++rr) {
        #pragma unroll
        for (int hh = 0; hh < 2; ++hh)
            #pragma unroll
            for (int cd = 0; cd < 4; ++cd)
                *reinterpret_cast<f32x4*>(&LDSf[w][hh][l16][cd * 16 + quad * 4]) = o[cd][rr * 2 + hh];
        __syncthreads();
        #pragma unroll
        for (int p = 0; p < 2; ++p) {
            const int item = tid + p * 512;            // 1024 items: 2 halves x 2 cq x 16 q x 16 d4
            const int h2 = item >> 9, rem = item & 511;
            const int j = rem >> 8, ql = (rem >> 4) & 15, d4 = (rem & 15) << 2;
            const int cq = rr * 2 + j;
            f32x4 acc = {};
            #pragma unroll
            for (int w2 = 0; w2 < 4; ++w2)
                acc += *reinterpret_cast<const f32x4*>(&LDSf[h2 * 4 + w2][j][ql][d4]);
            const int row = rowbase + h2 * 64 + cq * 16 + ql;
            *reinterpret_cast<f32x4*>(&Opart[((size_t)kh * (NB * SEQ) + row) * DK + d4]) = acc;
            if ((rem & 15) == 0) {
                float lq = 0.f;
                #pragma unroll
                for (int w2 = 0; w2 < 4; ++w2)
                    lq += LDSl[h2 * 4 + w2][cq][ql];
                Lpart[kh * (NB * SEQ) + row] = lq;
            }
        }
        __syncthreads();
    }
}

// ---------------- Kernel 3: combine key-half partials: O = (O0+O1)/(l0+l1) ---------------
__global__ __launch_bounds__(256) void comb_kernel(
    const float* __restrict__ Op, const float* __restrict__ Lp, float* __restrict__ out)
{
    const int idx = blockIdx.x * 256 + threadIdx.x;     // 65536 threads, 262144 f32x4 chunks
    #pragma unroll
    for (int it = 0; it < 4; ++it) {
        const int c = idx + it * 65536;
        const int row = c >> 4;
        const int d4 = (c & 15) << 2;
        f32x4 a = *reinterpret_cast<const f32x4*>(&Op[(size_t)row * DK + d4]);
        f32x4 b2 = *reinterpret_cast<const f32x4*>(&Op[(size_t)(NB * SEQ + row) * DK + d4]);
        float l = Lp[row] + Lp[NB * SEQ + row];
        f32x4 r = (a + b2) * (1.0f / l);
        *reinterpret_cast<f32x4*>(&out[(size_t)row * DK + d4]) = r;
    }
}

extern "C" void kernel_launch(void* const* d_in, const int* in_sizes, int n_in,
                              void* d_out, int out_size, void* d_ws, size_t ws_size,
                              hipStream_t stream) {
    const float* input1 = (const float*)d_in[0];
    const float* input2 = (const float*)d_in[1];
    const float* Wq = (const float*)d_in[2];
    const float* bq = (const float*)d_in[3];
    const float* Wk = (const float*)d_in[4];
    const float* bk = (const float*)d_in[5];
    const float* Wv = (const float*)d_in[6];
    const float* bv = (const float*)d_in[7];
    float* out = (float*)d_out;

    char* ws = (char*)d_ws;
    unsigned short* wtq = (unsigned short*)(ws + 0);
    unsigned short* wtk = (unsigned short*)(ws + 131072);
    unsigned short* wtv = (unsigned short*)(ws + 262144);
    unsigned short* Qw  = (unsigned short*)(ws + 393216);
    unsigned short* Kw  = (unsigned short*)(ws + 2490368);
    unsigned short* Vtw = (unsigned short*)(ws + 4587520);
    float* Opart = (float*)(ws + 6684672);     // [2][16384][64] f32 = 8 MB
    float* Lpart = (float*)(ws + 15073280);    // [2][16384] f32 = 128 KB

    wt_kernel<<<dim3(16, 3), 256, 0, stream>>>(Wq, Wk, Wv, wtq, wtk, wtv);
    proj_kernel<<<dim3(256, 2), 256, 0, stream>>>(input2, input1, wtq, wtk, wtv,
                                                  bq, bk, bv, Qw, Kw, Vtw);
    attn_kernel<<<dim3(256), 512, 0, stream>>>(Qw, Kw, Vtw, Opart, Lpart);
    comb_kernel<<<dim3(256), 256, 0, stream>>>(Opart, Lpart, out);
}